// Round 6
// baseline (705.690 us; speedup 1.0000x reference)
//
#include <hip/hip_runtime.h>
#include <math.h>

// E-Langevin sampler, fully fused: one kernel runs all 5 scan steps.
//  * rows independent -> one wave owns one row for the whole scan
//  * x binary -> x@W is a gather-sum of W rows; x_delta@W is an
//    incremental sparse update (~19.5 flipped bits/row/step)
//  * ROUND-6: rounds 0-5 showed an invariant 240-280us wall across all
//    VGPR/LDS/occupancy geometries -> in-flight gather bytes are capped
//    by the register file (every in-flight row costs 4 VGPRs x a wave
//    slot). Fix: global_load_lds DMA. Each wave owns an 8-slot/8KiB
//    LDS ring; W rows are DMA'd (zero VGPR cost) 8-deep in flight with
//    counted s_waitcnt vmcnt(4) (never 0 mid-stream), then consumed via
//    ds_read_b128: lane reads back exactly its own 16B = its 4 columns.
//    Identical values, identical (i asc, j asc) add order -> absmax 0.
//  * unified issue/consume cursors (scalar 4-way priority pop over the
//    four ballot masks, no runtime-indexed arrays -> no scratch) let
//    the pipeline run across i-group boundaries: ~1 latency exposure
//    per gather phase instead of 16 (init) / ~6 (per step).
//  * WAR safety: banks alternate; a bank is re-issued only after its
//    previous consume (lgkmcnt-blocked adds) and an asm memory fence,
//    and in-order wave issue makes overwrite-before-read impossible.
//  * 32KiB LDS/block (4 waves x 8KiB) -> 5 blocks/CU; no barriers.
//  * rr/noise/x/xa loads and out stores are non-temporal; next-step
//    prefetch is issued AFTER the counted-wait region so it flies over
//    pass C + reductions + next pass A.

namespace {

constexpr int kB = 16384;
constexpr int kD = 256;
constexpr int kSteps = 5;

typedef float v2f __attribute__((ext_vector_type(2)));
typedef float v4f __attribute__((ext_vector_type(4)));
typedef unsigned long long u64;

__device__ __forceinline__ v4f nt_load4(const float* p) {
  return __builtin_nontemporal_load(reinterpret_cast<const v4f*>(p));
}
__device__ __forceinline__ void nt_store4(float* p, v4f v) {
  __builtin_nontemporal_store(v, reinterpret_cast<v4f*>(p));
}

__device__ __forceinline__ float wave_sum(float v) {
#pragma unroll
  for (int off = 32; off > 0; off >>= 1) v += __shfl_xor(v, off, 64);
  return v;
}

__device__ __forceinline__ float sigmoid_f(float t) {
  if (t >= 0.0f) {
    float e = expf(-t);
    return 1.0f / (1.0f + e);
  } else {
    float e = expf(t);
    return e / (1.0f + e);
  }
}

// one-instruction DMA: each lane moves 16B from its gsrc to ldsbase+lane*16
__device__ __forceinline__ void dma16(const float* g, float* l) {
  __builtin_amdgcn_global_load_lds(
      (const __attribute__((address_space(1))) void*)g,
      (__attribute__((address_space(3))) void*)l, 16, 0, 0);
}

// pop lowest (i asc, j asc) set bit across the four i-group masks; d=4j+i
__device__ __forceinline__ int snext(u64& m0, u64& m1, u64& m2, u64& m3) {
  if (m0) { const int j = __builtin_ctzll(m0); m0 &= m0 - 1; return 4 * j + 0; }
  if (m1) { const int j = __builtin_ctzll(m1); m1 &= m1 - 1; return 4 * j + 1; }
  if (m2) { const int j = __builtin_ctzll(m2); m2 &= m2 - 1; return 4 * j + 2; }
  { const int j = __builtin_ctzll(m3); m3 &= m3 - 1; return 4 * j + 3; }
}

// same pop, but also produce the sign for the y2 sparse update
__device__ __forceinline__ float snext_sign(u64& m0, u64& m1, u64& m2, u64& m3,
                                            u64 s0, u64 s1, u64 s2, u64 s3) {
  if (m0) { const int j = __builtin_ctzll(m0); m0 &= m0 - 1;
            return ((s0 >> j) & 1ull) ? -1.0f : 1.0f; }
  if (m1) { const int j = __builtin_ctzll(m1); m1 &= m1 - 1;
            return ((s1 >> j) & 1ull) ? -1.0f : 1.0f; }
  if (m2) { const int j = __builtin_ctzll(m2); m2 &= m2 - 1;
            return ((s2 >> j) & 1ull) ? -1.0f : 1.0f; }
  { const int j = __builtin_ctzll(m3); m3 &= m3 - 1;
    return ((s3 >> j) & 1ull) ? -1.0f : 1.0f; }
}

__global__ __launch_bounds__(256) void els_fused(
    const float* __restrict__ x_in, const float* __restrict__ xa_in,
    const float* __restrict__ W, const float* __restrict__ bvec,
    const float* __restrict__ rr, const float* __restrict__ noise,
    const float* __restrict__ accept_u, float* __restrict__ out) {
  __shared__ float ring[4][8 * kD];  // 4 waves x 8 slots x 1KB = 32KiB

  const int tid = threadIdx.x;
  const int lane = tid & 63;
  const int wid = tid >> 6;
  const int row = blockIdx.x * 4 + wid;
  const int c0 = lane << 2;  // this lane owns columns c0..c0+3
  float* const ringw = &ring[wid][0];      // wave-uniform DMA dest base
  const float* const ringl = ringw + c0;   // lane's 16B within a slot
  const float* const Wl = W + c0;          // lane's 16B within a W row

  const v4f x4 = nt_load4(x_in + (size_t)row * kD + c0);
  const v4f a4 = nt_load4(xa_in + (size_t)row * kD + c0);
  const float4 b4 = *reinterpret_cast<const float4*>(bvec + c0);
  float xv[4] = {x4.x, x4.y, x4.z, x4.w};
  float xa[4] = {a4.x, a4.y, a4.z, a4.w};
  const float bv[4] = {b4.x, b4.y, b4.z, b4.w};
  v2f y01 = {0.0f, 0.0f}, y23 = {0.0f, 0.0f};

  // prefetch step 0 inputs (fly over the init gather)
  v4f r4 = nt_load4(rr + (size_t)row * kD + c0);
  v4f n4 = nt_load4(noise + (size_t)row * kD + c0);
  float u = accept_u[row];

  // ---- init: y = x @ W, DMA-ring pipelined gather, (i asc, j asc) ----
  {
    u64 b0 = __ballot(xv[0] > 0.5f);
    u64 b1 = __ballot(xv[1] > 0.5f);
    u64 b2 = __ballot(xv[2] > 0.5f);
    u64 b3 = __ballot(xv[3] > 0.5f);
    const int total = __popcll(b0) + __popcll(b1) + __popcll(b2) + __popcll(b3);
    const int chunks = (total + 3) >> 2;
    u64 a0 = b0, a1 = b1, a2 = b2, a3 = b3;  // issue cursor
    int issued = 0;
    auto issue4 = [&](int bank) {
#pragma unroll
      for (int q = 0; q < 4; ++q) {
        int d = 0;  // pad: harmless re-load of row 0, never consumed
        if (issued < total) { d = snext(a0, a1, a2, a3); ++issued; }
        dma16(Wl + (size_t)d * kD, ringw + (bank * 4 + q) * kD);
      }
    };
    if (total > 0) {
      issue4(0);
      int bk = 0, consumed = 0;
      for (int k = 0; k < chunks; ++k) {
        if (k + 1 < chunks) {
          issue4(bk ^ 1);
          asm volatile("s_waitcnt vmcnt(4)" ::: "memory");
        } else {
          asm volatile("s_waitcnt vmcnt(0)" ::: "memory");
        }
        __builtin_amdgcn_sched_barrier(0);
        const int n = (total - consumed < 4) ? (total - consumed) : 4;
#pragma unroll
        for (int q = 0; q < 4; ++q) {
          if (q < n) {
            const v4f w = *reinterpret_cast<const v4f*>(ringl + (bk * 4 + q) * kD);
            y01 += (v2f){w.x, w.y};
            y23 += (v2f){w.z, w.w};
          }
        }
        consumed += n;
        bk ^= 1;
      }
    }
  }

  for (int step = 0; step < kSteps; ++step) {
    const float rrv[4] = {r4.x, r4.y, r4.z, r4.w};
    const float nzv[4] = {n4.x, n4.y, n4.z, n4.w};
    const float ucur = u;

    const float yv[4] = {y01.x, y01.y, y23.x, y23.y};
    float ga[4], xd[4], xda[4];
    bool ind[4];
    float s_lpf = 0.f, s_xy = 0.f, s_xb = 0.f, s_sqc = 0.f, s_fwd = 0.f;
    u64 fm0, fm1, fm2, fm3, sm0, sm1, sm2, sm3;

    // pass A: flip decisions + proposals + forward sums (r0 order)
#pragma unroll
    for (int i = 0; i < 4; ++i) {
      ga[i] = (xv[i] - xa[i]) / 1.0e4f;                 // agrad, ETA=1e4
      const float sgn = 1.0f - 2.0f * xv[i];            // -(2x-1)
      const float gm = (yv[i] + bv[i] - ga[i]) * sgn / 2.0f;  // TEMP=2
      const float p = sigmoid_f(gm - 2.5f);             // term2 = 1/(2*0.2)
      ind[i] = rrv[i] < p;
      xd[i] = ind[i] ? 1.0f - xv[i] : xv[i];
      xda[i] = xa[i] + 0.25f * ga[i] + 0.70710678118654752f * nzv[i];
      const float pr = ind[i] ? p : 1.0f - p;
      s_lpf += logf(pr + 1e-10f);
      s_xy += xv[i] * yv[i];
      s_xb += xv[i] * bv[i];
      const float dc = xv[i] - xa[i];
      s_sqc += dc * dc;
      const float fw = xda[i] - (xa[i] + 0.25f * ga[i]);
      s_fwd += fw * fw;
      const u64 fmb = __ballot(ind[i]);
      const u64 smb = __ballot(xv[i] > 0.5f);  // flip 1->0 subtracts the row
      if (i == 0) { fm0 = fmb; sm0 = smb; }
      else if (i == 1) { fm1 = fmb; sm1 = smb; }
      else if (i == 2) { fm2 = fmb; sm2 = smb; }
      else { fm3 = fmb; sm3 = smb; }
    }

    // ---- y2 = x_delta @ W, DMA-ring pipelined sparse update ----
    v2f y2lo = y01, y2hi = y23;
    {
      const int total = __popcll(fm0) + __popcll(fm1) + __popcll(fm2) + __popcll(fm3);
      const int chunks = (total + 3) >> 2;
      u64 a0 = fm0, a1 = fm1, a2 = fm2, a3 = fm3;  // issue cursor
      u64 c0m = fm0, c1m = fm1, c2m = fm2, c3m = fm3;  // consume cursor
      int issued = 0;
      auto issue4 = [&](int bank) {
#pragma unroll
        for (int q = 0; q < 4; ++q) {
          int d = 0;
          if (issued < total) { d = snext(a0, a1, a2, a3); ++issued; }
          dma16(Wl + (size_t)d * kD, ringw + (bank * 4 + q) * kD);
        }
      };
      if (total > 0) {
        issue4(0);
        int bk = 0, consumed = 0;
        for (int k = 0; k < chunks; ++k) {
          if (k + 1 < chunks) {
            issue4(bk ^ 1);
            asm volatile("s_waitcnt vmcnt(4)" ::: "memory");
          } else {
            asm volatile("s_waitcnt vmcnt(0)" ::: "memory");
          }
          __builtin_amdgcn_sched_barrier(0);
          const int n = (total - consumed < 4) ? (total - consumed) : 4;
#pragma unroll
          for (int q = 0; q < 4; ++q) {
            if (q < n) {
              const float s =
                  snext_sign(c0m, c1m, c2m, c3m, sm0, sm1, sm2, sm3);
              const v4f w =
                  *reinterpret_cast<const v4f*>(ringl + (bk * 4 + q) * kD);
              const v2f sv = {s, s};
              y2lo = __builtin_elementwise_fma(sv, (v2f){w.x, w.y}, y2lo);
              y2hi = __builtin_elementwise_fma(sv, (v2f){w.z, w.w}, y2hi);
            }
          }
          consumed += n;
          bk ^= 1;
        }
      }
    }

    // prefetch NEXT step's inputs AFTER the counted-wait region; they fly
    // over pass C + reductions + next pass A
    const int sn = (step + 1 < kSteps) ? step + 1 : step;
    const size_t offn = ((size_t)sn * kB + row) * kD + c0;
    r4 = nt_load4(rr + offn);
    n4 = nt_load4(noise + offn);
    u = accept_u[(size_t)sn * kB + row];

    const float y2v[4] = {y2lo.x, y2lo.y, y2hi.x, y2hi.y};
    float s_lpr = 0.f, s_xdy = 0.f, s_xdb = 0.f, s_sqn = 0.f, s_rev = 0.f;
#pragma unroll
    for (int i = 0; i < 4; ++i) {
      const float ga2 = (xd[i] - xda[i]) / 1.0e4f;
      const float sgn2 = 1.0f - 2.0f * xd[i];
      const float gm2 = (y2v[i] + bv[i] - ga2) * sgn2 / 2.0f;
      const float p2 = sigmoid_f(gm2 - 2.5f);
      const float pr2 = ind[i] ? p2 : 1.0f - p2;
      s_lpr += logf(pr2 + 1e-10f);
      s_xdy += xd[i] * y2v[i];
      s_xdb += xd[i] * bv[i];
      const float dn = xd[i] - xda[i];
      s_sqn += dn * dn;
      const float rv = xa[i] - (xda[i] + 0.25f * ga2);
      s_rev += rv * rv;
    }

    // row reductions (wave = row)
    s_lpf = wave_sum(s_lpf);
    s_lpr = wave_sum(s_lpr);
    s_xy = wave_sum(s_xy);
    s_xb = wave_sum(s_xb);
    s_xdy = wave_sum(s_xdy);
    s_xdb = wave_sum(s_xdb);
    s_sqc = wave_sum(s_sqc);
    s_sqn = wave_sum(s_sqn);
    s_rev = wave_sum(s_rev);
    s_fwd = wave_sum(s_fwd);

    const float E_cur = 0.5f * s_xy + s_xb;
    const float E_new = 0.5f * s_xdy + s_xdb;
    const float m_term = (E_new - s_sqn / 2.0e4f) - (E_cur - s_sqc / 2.0e4f);
    // add_rev = s_rev / (-2*ALPHA_A) = -s_rev ; add_fwd = -s_fwd
    const float la = m_term - s_rev + s_fwd + s_lpr - s_lpf;
    const bool acc = la > logf(ucur);

#pragma unroll
    for (int i = 0; i < 4; ++i) {
      xv[i] = acc ? xd[i] : xv[i];
      xa[i] = acc ? xda[i] : xa[i];
    }
    y01 = acc ? y2lo : y01;
    y23 = acc ? y2hi : y23;
  }

  const v4f ox = {xv[0], xv[1], xv[2], xv[3]};
  const v4f oa = {xa[0], xa[1], xa[2], xa[3]};
  nt_store4(out + (size_t)row * kD + c0, ox);
  nt_store4(out + (size_t)kB * kD + (size_t)row * kD + c0, oa);
}

}  // namespace

extern "C" void kernel_launch(void* const* d_in, const int* in_sizes, int n_in,
                              void* d_out, int out_size, void* d_ws, size_t ws_size,
                              hipStream_t stream) {
  const float* x = (const float*)d_in[0];
  const float* xa = (const float*)d_in[1];
  const float* W = (const float*)d_in[2];
  const float* b = (const float*)d_in[3];
  const float* rr = (const float*)d_in[4];
  const float* noise = (const float*)d_in[5];
  const float* au = (const float*)d_in[6];
  float* out = (float*)d_out;

  dim3 grid(kB / 4);
  dim3 block(256);
  hipLaunchKernelGGL(els_fused, grid, block, 0, stream, x, xa, W, b, rr, noise,
                     au, out);
}